// Round 21
// baseline (246.743 us; speedup 1.0000x reference)
//
#include <hip/hip_runtime.h>
#include <hip/hip_bf16.h>
#include <stdint.h>

typedef __attribute__((ext_vector_type(8))) short short8;
typedef __attribute__((ext_vector_type(16))) float f32x16;

#define CD 256   // channels
#define HD 512   // hidden

// ---------- helpers ----------
static __device__ __forceinline__ unsigned short f2bf(float f) {
    union { float f; unsigned int u; } cv; cv.f = f;
    unsigned int u = cv.u;
    unsigned int r = u + 0x7FFFu + ((u >> 16) & 1u);   // round-to-nearest-even
    return (unsigned short)(r >> 16);
}
static __device__ __forceinline__ unsigned int pack2(unsigned short a, unsigned short b) {
    return (unsigned int)a | ((unsigned int)b << 16);
}

#define LOG2E 1.44269504f
#define LN2   0.69314718f

// ---------- kernel 1: fused prep -- (Wt*log2e) fp32->bf16 + batch->int32 ----------
// Pre-scaling Wt by log2e folds the exp2-argument multiply into the MFMA itself:
// w = x.(Wt*log2e)^T + bt*log2e, softplus*wg = log2(1+exp2(w)) * (wg*ln2).
__global__ void prep_kernel(const float* __restrict__ wt, unsigned short* __restrict__ wtb,
                            const void* __restrict__ batch, int* __restrict__ b32, int n) {
    const int blk = blockIdx.x;
    if (blk < 64) {
        int t = blk * 256 + threadIdx.x;               // 16384 granules
        const float4* p = (const float4*)wt;
        float4 f0 = p[t * 2], f1 = p[t * 2 + 1];
        uint4 v;
        v.x = pack2(f2bf(f0.x * LOG2E), f2bf(f0.y * LOG2E));
        v.y = pack2(f2bf(f0.z * LOG2E), f2bf(f0.w * LOG2E));
        v.z = pack2(f2bf(f1.x * LOG2E), f2bf(f1.y * LOG2E));
        v.w = pack2(f2bf(f1.z * LOG2E), f2bf(f1.w * LOG2E));
        ((uint4*)wtb)[t] = v;
    } else {
        const long long* p64 = (const long long*)batch;
        const int* p32 = (const int*)batch;
        bool is64 = ((unsigned long long)p64[n / 2 - 1]) < (1ull << 20);
        for (int i = (blk - 64) * 256 + threadIdx.x; i < n; i += 512 * 256)
            b32[i] = is64 ? (int)p64[i] : p32[i];
    }
}

// ---------- kernel 2: gate logits (v19 = R20 + epilogue(c-1) overlaps MFMA(c)) ----------
// 128 rows/block, 4 waves x 32 rows. R20's proven 2-buf shell (36KB LDS, plain
// launch bounds, vmcnt(0)+raw barrier, full-tile fast path). NEW: two named
// accumulator sets; region c runs MFMA(c->accX) with SOFTPLUS(c-1, accY)
// interleaved by the scheduler -- the wave issues softplus VALU/trans ops into
// the dependent-MFMA-chain latency gaps (mechanism validated by R20's win).
// Live set ~127 regs; plain bounds leave the allocator free (R12's spill was
// the (256,3)->84-reg cap, not the structure).
__global__ __launch_bounds__(256) void gate_kernel(
    const float* __restrict__ x, const unsigned short* __restrict__ wtb,
    const float* __restrict__ bt, const float* __restrict__ wg,
    const float* __restrict__ bg, float* __restrict__ logits, int n)
{
    __shared__ __align__(16) char lds[36864];   // 2x16KB Wt bufs + 2KB bt' + 2KB wg'
    const int tid = threadIdx.x;
    const int lane = tid & 63;
    const int wid = tid >> 6;
    const int l31 = lane & 31;
    const int g = lane >> 5;                    // k-half 0/1
    const long rowbase = (long)blockIdx.x * 128;

    // ---- stage bt*log2e / wg*ln2 -> LDS
    {
        float2 b2 = ((const float2*)bt)[tid];
        float2 w2 = ((const float2*)wg)[tid];
        b2.x *= LOG2E; b2.y *= LOG2E;
        w2.x *= LN2;   w2.y *= LN2;
        *(float2*)(lds + 32768 + tid * 8) = b2;
        *(float2*)(lds + 34816 + tid * 8) = w2;
    }

    // ---- A fragments: direct global loads, cvt in-reg
    short8 a[16];
    {
        const long row = rowbase + wid * 32 + l31;
        const float4* xr = (const float4*)(x + row * 256) + g * 2;
#define CVT_A(kt, F0, F1)                                                             \
        {                                                                             \
            __hip_bfloat162 p0 = __float22bfloat162_rn(make_float2((F0).x, (F0).y));  \
            __hip_bfloat162 p1 = __float22bfloat162_rn(make_float2((F0).z, (F0).w));  \
            __hip_bfloat162 p2 = __float22bfloat162_rn(make_float2((F1).x, (F1).y));  \
            __hip_bfloat162 p3 = __float22bfloat162_rn(make_float2((F1).z, (F1).w));  \
            union { uint4 u; short8 s; } cv;                                          \
            cv.u = make_uint4(*(unsigned int*)&p0, *(unsigned int*)&p1,               \
                              *(unsigned int*)&p2, *(unsigned int*)&p3);              \
            a[kt] = cv.s;                                                             \
        }
        if (rowbase + 128 <= (long)n) {         // full tile: unguarded (the hot path)
#pragma unroll
            for (int kt = 0; kt < 16; ++kt) {
                float4 f0 = xr[kt * 4];
                float4 f1 = xr[kt * 4 + 1];
                CVT_A(kt, f0, f1)
            }
        } else {
            const bool ok = row < (long)n;
#pragma unroll
            for (int kt = 0; kt < 16; ++kt) {
                float4 f0 = ok ? xr[kt * 4]     : make_float4(0.f, 0.f, 0.f, 0.f);
                float4 f1 = ok ? xr[kt * 4 + 1] : make_float4(0.f, 0.f, 0.f, 0.f);
                CVT_A(kt, f0, f1)
            }
        }
#undef CVT_A
    }

    // per-lane Wt source offsets: physical granule p holds logical (rc, (p&31)^rc)
    int soff[4];
#pragma unroll
    for (int i = 0; i < 4; ++i) {
        int p = (wid * 4 + i) * 64 + lane;
        int rc = p >> 5;
        int gcl = (p & 31) ^ (rc & 31);
        soff[i] = rc * 512 + gcl * 16;
    }
    const char* wtbb = (const char*)wtb;

#define STAGE(c, bufoff)                                                              \
    {                                                                                 \
        const char* src = wtbb + (c) * 16384;                                         \
        char* dst = lds + (bufoff) + wid * 4096;                                      \
        _Pragma("unroll")                                                             \
        for (int i = 0; i < 4; ++i)                                                   \
            __builtin_amdgcn_global_load_lds(                                         \
                (const __attribute__((address_space(1))) unsigned int*)(src + soff[i]), \
                (__attribute__((address_space(3))) unsigned int*)(dst + i * 1024),    \
                16, 0, 0);                                                            \
    }

    // MFMA chunk c into ACC (fresh accumulation)
#define MFMA_CHUNK(c, ACC)                                                            \
    {                                                                                 \
        const char* bb = lds + ((c) & 1) * 16384 + l31 * 512;                         \
        _Pragma("unroll")                                                             \
        for (int r = 0; r < 16; ++r) ACC[r] = 0.f;                                    \
        _Pragma("unroll")                                                             \
        for (int kt = 0; kt < 16; ++kt) {                                             \
            short8 b = *(const short8*)(bb + (((kt * 2 + g) ^ l31) * 16));            \
            ACC = __builtin_amdgcn_mfma_f32_32x32x16_bf16(a[kt], b, ACC, 0, 0, 0);    \
        }                                                                             \
    }

    // softplus epilogue for chunk c held in PACC: lp += log2(1+exp2(w)) * wg'
#define SOFTPLUS(c, PACC)                                                             \
    {                                                                                 \
        const float btv = *(const float*)(lds + 32768 + ((c) * 32 + l31) * 4);        \
        const float wgv = *(const float*)(lds + 34816 + ((c) * 32 + l31) * 4);        \
        _Pragma("unroll")                                                             \
        for (int r = 0; r < 16; ++r) {                                                \
            float w = PACC[r] + btv;                                                  \
            float sp = __builtin_amdgcn_logf(1.0f + __builtin_amdgcn_exp2f(w));       \
            lp[r] = fmaf(sp, wgv, lp[r]);                                             \
        }                                                                             \
    }

    // region: retire stage(c), prefetch stage(c+1), MFMA(c) overlapped w/ softplus(c-1)
#define REGION(c, ACC, PACC)                                                          \
    {                                                                                 \
        asm volatile("s_waitcnt vmcnt(0)" ::: "memory");                              \
        __builtin_amdgcn_s_barrier();                                                 \
        if ((c) < 15) STAGE((c) + 1, (((c) + 1) & 1) * 16384);                        \
        MFMA_CHUNK(c, ACC)                                                            \
        SOFTPLUS((c) - 1, PACC)                                                       \
    }

    float lp[16];
    f32x16 accA, accB;
#pragma unroll
    for (int r = 0; r < 16; ++r) lp[r] = 0.f;

    __syncthreads();            // bt/wg visible; all prior vmem drained (A consumed)

    STAGE(0, 0);

    // region 0 (no previous softplus)
    asm volatile("s_waitcnt vmcnt(0)" ::: "memory");
    __builtin_amdgcn_s_barrier();
    STAGE(1, 16384);
    MFMA_CHUNK(0, accA)

#pragma unroll 1
    for (int c = 1; c < 15; c += 2) {
        REGION(c, accB, accA)             // MFMA(c)->accB, softplus(c-1) from accA
        REGION(c + 1, accA, accB)         // MFMA(c+1)->accA, softplus(c) from accB
    }
    // region 15 (c=15 odd -> accB; c=14 even left result in accA)
    {
        asm volatile("s_waitcnt vmcnt(0)" ::: "memory");
        __builtin_amdgcn_s_barrier();
        MFMA_CHUNK(15, accB)
        SOFTPLUS(14, accA)
    }
    SOFTPLUS(15, accB)
#undef REGION
#undef SOFTPLUS
#undef MFMA_CHUNK
#undef STAGE

    // reduce over the 32 h-lanes within each half, write logits
#pragma unroll
    for (int r = 0; r < 16; ++r) {
        float v = lp[r];
        v += __shfl_xor(v, 1);
        v += __shfl_xor(v, 2);
        v += __shfl_xor(v, 4);
        v += __shfl_xor(v, 8);
        v += __shfl_xor(v, 16);
        lp[r] = v;
    }
    if (l31 == 0) {
        const float bgv = bg[0];
#pragma unroll
        for (int r = 0; r < 16; ++r) {
            long row = rowbase + wid * 32 + 4 * g + (r & 3) + 8 * (r >> 2);  // C/D layout (m74/m101)
            if (row < (long)n) logits[row] = lp[r] + bgv;
        }
    }
}

// ---------- kernel 3: fused segment stats + pooling ----------
static __device__ __forceinline__ int lower_bound(const int* __restrict__ a, int n, int v) {
    int lo = 0, hi = n;
    while (lo < hi) { int mid = (lo + hi) >> 1; if (a[mid] < v) lo = mid + 1; else hi = mid; }
    return lo;
}

__global__ __launch_bounds__(256) void segpool_kernel(const float* __restrict__ x,
    const float* __restrict__ logits, const int* __restrict__ batch,
    float* __restrict__ out, int n)
{
    __shared__ float wsh[1024];
    __shared__ float sh_red[4];
    __shared__ int sh_se[2];
    const int b = blockIdx.x;
    const int tid = threadIdx.x;

    if (tid == 0) {
        sh_se[0] = lower_bound(batch, n, b);
        sh_se[1] = lower_bound(batch, n, b + 1);
    }
    __syncthreads();
    const int start = sh_se[0], end = sh_se[1];
    const int cnt = end - start;

    // ---- segment max
    float m = -3.4e38f;
    for (int i = start + tid; i < end; i += 256) m = fmaxf(m, logits[i]);
#pragma unroll
    for (int mk = 1; mk <= 32; mk <<= 1) m = fmaxf(m, __shfl_xor(m, mk));
    if ((tid & 63) == 0) sh_red[tid >> 6] = m;
    __syncthreads();
    m = fmaxf(fmaxf(sh_red[0], sh_red[1]), fmaxf(sh_red[2], sh_red[3]));
    __syncthreads();

    // ---- segment sum of exp
    float s = 0.f;
    for (int i = start + tid; i < end; i += 256) s += __expf(logits[i] - m);
#pragma unroll
    for (int mk = 1; mk <= 32; mk <<= 1) s += __shfl_xor(s, mk);
    if ((tid & 63) == 0) sh_red[tid >> 6] = s;
    __syncthreads();
    s = sh_red[0] + sh_red[1] + sh_red[2] + sh_red[3];

    const float srs = (s > 0.f) ? (1.f / s) : 0.f;
    const float sinv = 1.f / (float)((cnt > 0) ? cnt : 1);

    // ---- pooling pass (weights staged 1024 at a time in LDS)
    float acc = 0.f;
    const int c = tid;
    for (int base = 0; base < cnt; base += 1024) {
        const int mm = min(cnt - base, 1024);
        __syncthreads();
        for (int i = c; i < mm; i += 256)
            wsh[i] = __expf(logits[start + base + i] - m) * srs + sinv;
        __syncthreads();
        const float* xp = x + (size_t)(start + base) * CD + c;
        int i = 0;
        for (; i + 8 <= mm; i += 8) {
            float x0 = xp[(size_t)(i+0)*CD], x1 = xp[(size_t)(i+1)*CD];
            float x2 = xp[(size_t)(i+2)*CD], x3 = xp[(size_t)(i+3)*CD];
            float x4 = xp[(size_t)(i+4)*CD], x5 = xp[(size_t)(i+5)*CD];
            float x6 = xp[(size_t)(i+6)*CD], x7 = xp[(size_t)(i+7)*CD];
            acc = fmaf(wsh[i+0],x0,fmaf(wsh[i+1],x1,fmaf(wsh[i+2],x2,fmaf(wsh[i+3],x3,acc))));
            acc = fmaf(wsh[i+4],x4,fmaf(wsh[i+5],x5,fmaf(wsh[i+6],x6,fmaf(wsh[i+7],x7,acc))));
        }
        for (; i < mm; ++i) acc = fmaf(wsh[i], xp[(size_t)i*CD], acc);
    }
    out[(size_t)b * CD + c] = acc;
}

// ---------- launcher ----------
extern "C" void kernel_launch(void* const* d_in, const int* in_sizes, int n_in,
                              void* d_out, int out_size, void* d_ws, size_t ws_size,
                              hipStream_t stream)
{
    const float* x  = (const float*)d_in[0];
    const void*  batch = d_in[1];
    const float* Wt = (const float*)d_in[3];
    const float* bt = (const float*)d_in[4];
    const float* Wg = (const float*)d_in[5];
    const float* bg = (const float*)d_in[6];
    float* out = (float*)d_out;
    const int n = in_sizes[1];            // 400000
    const int nseg = out_size / CD;       // 1024

    char* ws = (char*)d_ws;
    size_t off = 0;
    unsigned short* wtb = (unsigned short*)(ws + off); off += (size_t)HD * CD * 2;
    float* logits = (float*)(ws + off); off += (size_t)n * 4;
    int* batch32  = (int*)(ws + off);   off += (size_t)n * 4;

    hipLaunchKernelGGL(prep_kernel, dim3(576), dim3(256), 0, stream, Wt, wtb, batch, batch32, n);
    hipLaunchKernelGGL(gate_kernel, dim3((n + 127) / 128), dim3(256), 0, stream,
                       x, wtb, bt, Wg, bg, logits, n);
    hipLaunchKernelGGL(segpool_kernel, dim3(nseg), dim3(256), 0, stream,
                       x, logits, batch32, out, n);
}

// Round 22
// 233.734 us; speedup vs baseline: 1.0557x; 1.0557x over previous
//
#include <hip/hip_runtime.h>
#include <hip/hip_bf16.h>
#include <stdint.h>

typedef __attribute__((ext_vector_type(8))) short short8;
typedef __attribute__((ext_vector_type(16))) float f32x16;

#define CD 256   // channels
#define HD 512   // hidden

// ---------- helpers ----------
static __device__ __forceinline__ unsigned short f2bf(float f) {
    union { float f; unsigned int u; } cv; cv.f = f;
    unsigned int u = cv.u;
    unsigned int r = u + 0x7FFFu + ((u >> 16) & 1u);   // round-to-nearest-even
    return (unsigned short)(r >> 16);
}
static __device__ __forceinline__ unsigned int pack2(unsigned short a, unsigned short b) {
    return (unsigned int)a | ((unsigned int)b << 16);
}

#define LOG2E 1.44269504f
#define LN2   0.69314718f

// ---------- kernel 1: fused prep -- (Wt*log2e) fp32->bf16 + batch->int32 ----------
// Pre-scaling Wt by log2e folds the exp2-argument multiply into the MFMA:
// w = x.(Wt*log2e)^T + bt*log2e;  softplus*wg = log2(1+exp2(w)) * (wg*ln2).
// Epilogue per value: add, exp2, add, log2, fma (5 serial ops vs R20's 7).
__global__ void prep_kernel(const float* __restrict__ wt, unsigned short* __restrict__ wtb,
                            const void* __restrict__ batch, int* __restrict__ b32, int n) {
    const int blk = blockIdx.x;
    if (blk < 64) {
        int t = blk * 256 + threadIdx.x;               // 16384 granules
        const float4* p = (const float4*)wt;
        float4 f0 = p[t * 2], f1 = p[t * 2 + 1];
        uint4 v;
        v.x = pack2(f2bf(f0.x * LOG2E), f2bf(f0.y * LOG2E));
        v.y = pack2(f2bf(f0.z * LOG2E), f2bf(f0.w * LOG2E));
        v.z = pack2(f2bf(f1.x * LOG2E), f2bf(f1.y * LOG2E));
        v.w = pack2(f2bf(f1.z * LOG2E), f2bf(f1.w * LOG2E));
        ((uint4*)wtb)[t] = v;
    } else {
        const long long* p64 = (const long long*)batch;
        const int* p32 = (const int*)batch;
        bool is64 = ((unsigned long long)p64[n / 2 - 1]) < (1ull << 20);
        for (int i = (blk - 64) * 256 + threadIdx.x; i < n; i += 512 * 256)
            b32[i] = is64 ? (int)p64[i] : p32[i];
    }
}

// ---------- kernel 2: gate logits (v20 = R20 shell + folded constants) ----------
// 128 rows/block, 4 waves x 32 rows. A-frags direct from global (bf16 in-reg cvt);
// full-tile fast path. Wt: 16 chunks of 32h, 2 rotating 16KB LDS bufs, rolled
// loop + raw s_barrier + vmcnt(0) (stage issued one full region early). SINGLE
// accumulator, softplus immediately after MFMA (R20's proven form) -- the
// dual-acc overlap regressed twice (R12, R21) and is retired.
__global__ __launch_bounds__(256) void gate_kernel(
    const float* __restrict__ x, const unsigned short* __restrict__ wtb,
    const float* __restrict__ bt, const float* __restrict__ wg,
    const float* __restrict__ bg, float* __restrict__ logits, int n)
{
    __shared__ __align__(16) char lds[36864];   // 2x16KB Wt bufs + 2KB bt' + 2KB wg'
    const int tid = threadIdx.x;
    const int lane = tid & 63;
    const int wid = tid >> 6;
    const int l31 = lane & 31;
    const int g = lane >> 5;                    // k-half 0/1
    const long rowbase = (long)blockIdx.x * 128;

    // ---- stage bt*log2e / wg*ln2 -> LDS
    {
        float2 b2 = ((const float2*)bt)[tid];
        float2 w2 = ((const float2*)wg)[tid];
        b2.x *= LOG2E; b2.y *= LOG2E;
        w2.x *= LN2;   w2.y *= LN2;
        *(float2*)(lds + 32768 + tid * 8) = b2;
        *(float2*)(lds + 34816 + tid * 8) = w2;
    }

    // ---- A fragments: direct global loads, cvt in-reg
    short8 a[16];
    {
        const long row = rowbase + wid * 32 + l31;
        const float4* xr = (const float4*)(x + row * 256) + g * 2;
#define CVT_A(kt, F0, F1)                                                             \
        {                                                                             \
            __hip_bfloat162 p0 = __float22bfloat162_rn(make_float2((F0).x, (F0).y));  \
            __hip_bfloat162 p1 = __float22bfloat162_rn(make_float2((F0).z, (F0).w));  \
            __hip_bfloat162 p2 = __float22bfloat162_rn(make_float2((F1).x, (F1).y));  \
            __hip_bfloat162 p3 = __float22bfloat162_rn(make_float2((F1).z, (F1).w));  \
            union { uint4 u; short8 s; } cv;                                          \
            cv.u = make_uint4(*(unsigned int*)&p0, *(unsigned int*)&p1,               \
                              *(unsigned int*)&p2, *(unsigned int*)&p3);              \
            a[kt] = cv.s;                                                             \
        }
        if (rowbase + 128 <= (long)n) {         // full tile: unguarded (the hot path)
#pragma unroll
            for (int kt = 0; kt < 16; ++kt) {
                float4 f0 = xr[kt * 4];
                float4 f1 = xr[kt * 4 + 1];
                CVT_A(kt, f0, f1)
            }
        } else {
            const bool ok = row < (long)n;
#pragma unroll
            for (int kt = 0; kt < 16; ++kt) {
                float4 f0 = ok ? xr[kt * 4]     : make_float4(0.f, 0.f, 0.f, 0.f);
                float4 f1 = ok ? xr[kt * 4 + 1] : make_float4(0.f, 0.f, 0.f, 0.f);
                CVT_A(kt, f0, f1)
            }
        }
#undef CVT_A
    }

    // per-lane Wt source offsets: physical granule p holds logical (rc, (p&31)^rc)
    int soff[4];
#pragma unroll
    for (int i = 0; i < 4; ++i) {
        int p = (wid * 4 + i) * 64 + lane;
        int rc = p >> 5;
        int gcl = (p & 31) ^ (rc & 31);
        soff[i] = rc * 512 + gcl * 16;
    }
    const char* wtbb = (const char*)wtb;

#define STAGE(c, bufoff)                                                              \
    {                                                                                 \
        const char* src = wtbb + (c) * 16384;                                         \
        char* dst = lds + (bufoff) + wid * 4096;                                      \
        _Pragma("unroll")                                                             \
        for (int i = 0; i < 4; ++i)                                                   \
            __builtin_amdgcn_global_load_lds(                                         \
                (const __attribute__((address_space(1))) unsigned int*)(src + soff[i]), \
                (__attribute__((address_space(3))) unsigned int*)(dst + i * 1024),    \
                16, 0, 0);                                                            \
    }

#define COMPUTE(c)                                                                    \
    {                                                                                 \
        const char* bb = lds + ((c) & 1) * 16384 + l31 * 512;                         \
        f32x16 acc;                                                                   \
        _Pragma("unroll")                                                             \
        for (int r = 0; r < 16; ++r) acc[r] = 0.f;                                    \
        _Pragma("unroll")                                                             \
        for (int kt = 0; kt < 16; ++kt) {                                             \
            short8 b = *(const short8*)(bb + (((kt * 2 + g) ^ l31) * 16));            \
            acc = __builtin_amdgcn_mfma_f32_32x32x16_bf16(a[kt], b, acc, 0, 0, 0);    \
        }                                                                             \
        const float btv = *(const float*)(lds + 32768 + ((c) * 32 + l31) * 4);        \
        const float wgv = *(const float*)(lds + 34816 + ((c) * 32 + l31) * 4);        \
        _Pragma("unroll")                                                             \
        for (int r = 0; r < 16; ++r) {                                                \
            float w = acc[r] + btv;                                                   \
            float sp = __builtin_amdgcn_logf(1.0f + __builtin_amdgcn_exp2f(w));       \
            lp[r] = fmaf(sp, wgv, lp[r]);                                             \
        }                                                                             \
    }

    float lp[16];
#pragma unroll
    for (int r = 0; r < 16; ++r) lp[r] = 0.f;

    __syncthreads();            // bt/wg visible; all prior vmem drained (A consumed)

    STAGE(0, 0);

#pragma unroll 1
    for (int c = 0; c < 16; ++c) {
        // outstanding here = stage(c) only, issued one full region earlier
        asm volatile("s_waitcnt vmcnt(0)" ::: "memory");
        __builtin_amdgcn_s_barrier();   // stage(c) visible to all; buf[(c+1)&1] free
        if (c < 15) STAGE(c + 1, ((c + 1) & 1) * 16384);
        COMPUTE(c);
    }
#undef COMPUTE
#undef STAGE

    // reduce over the 32 h-lanes within each half, write logits
#pragma unroll
    for (int r = 0; r < 16; ++r) {
        float v = lp[r];
        v += __shfl_xor(v, 1);
        v += __shfl_xor(v, 2);
        v += __shfl_xor(v, 4);
        v += __shfl_xor(v, 8);
        v += __shfl_xor(v, 16);
        lp[r] = v;
    }
    if (l31 == 0) {
        const float bgv = bg[0];
#pragma unroll
        for (int r = 0; r < 16; ++r) {
            long row = rowbase + wid * 32 + 4 * g + (r & 3) + 8 * (r >> 2);  // C/D layout (m74/m101)
            if (row < (long)n) logits[row] = lp[r] + bgv;
        }
    }
}

// ---------- kernel 3: fused segment stats + pooling ----------
static __device__ __forceinline__ int lower_bound(const int* __restrict__ a, int n, int v) {
    int lo = 0, hi = n;
    while (lo < hi) { int mid = (lo + hi) >> 1; if (a[mid] < v) lo = mid + 1; else hi = mid; }
    return lo;
}

__global__ __launch_bounds__(256) void segpool_kernel(const float* __restrict__ x,
    const float* __restrict__ logits, const int* __restrict__ batch,
    float* __restrict__ out, int n)
{
    __shared__ float wsh[1024];
    __shared__ float sh_red[4];
    __shared__ int sh_se[2];
    const int b = blockIdx.x;
    const int tid = threadIdx.x;

    if (tid == 0) {
        sh_se[0] = lower_bound(batch, n, b);
        sh_se[1] = lower_bound(batch, n, b + 1);
    }
    __syncthreads();
    const int start = sh_se[0], end = sh_se[1];
    const int cnt = end - start;

    // ---- segment max
    float m = -3.4e38f;
    for (int i = start + tid; i < end; i += 256) m = fmaxf(m, logits[i]);
#pragma unroll
    for (int mk = 1; mk <= 32; mk <<= 1) m = fmaxf(m, __shfl_xor(m, mk));
    if ((tid & 63) == 0) sh_red[tid >> 6] = m;
    __syncthreads();
    m = fmaxf(fmaxf(sh_red[0], sh_red[1]), fmaxf(sh_red[2], sh_red[3]));
    __syncthreads();

    // ---- segment sum of exp
    float s = 0.f;
    for (int i = start + tid; i < end; i += 256) s += __expf(logits[i] - m);
#pragma unroll
    for (int mk = 1; mk <= 32; mk <<= 1) s += __shfl_xor(s, mk);
    if ((tid & 63) == 0) sh_red[tid >> 6] = s;
    __syncthreads();
    s = sh_red[0] + sh_red[1] + sh_red[2] + sh_red[3];

    const float srs = (s > 0.f) ? (1.f / s) : 0.f;
    const float sinv = 1.f / (float)((cnt > 0) ? cnt : 1);

    // ---- pooling pass (weights staged 1024 at a time in LDS)
    float acc = 0.f;
    const int c = tid;
    for (int base = 0; base < cnt; base += 1024) {
        const int mm = min(cnt - base, 1024);
        __syncthreads();
        for (int i = c; i < mm; i += 256)
            wsh[i] = __expf(logits[start + base + i] - m) * srs + sinv;
        __syncthreads();
        const float* xp = x + (size_t)(start + base) * CD + c;
        int i = 0;
        for (; i + 8 <= mm; i += 8) {
            float x0 = xp[(size_t)(i+0)*CD], x1 = xp[(size_t)(i+1)*CD];
            float x2 = xp[(size_t)(i+2)*CD], x3 = xp[(size_t)(i+3)*CD];
            float x4 = xp[(size_t)(i+4)*CD], x5 = xp[(size_t)(i+5)*CD];
            float x6 = xp[(size_t)(i+6)*CD], x7 = xp[(size_t)(i+7)*CD];
            acc = fmaf(wsh[i+0],x0,fmaf(wsh[i+1],x1,fmaf(wsh[i+2],x2,fmaf(wsh[i+3],x3,acc))));
            acc = fmaf(wsh[i+4],x4,fmaf(wsh[i+5],x5,fmaf(wsh[i+6],x6,fmaf(wsh[i+7],x7,acc))));
        }
        for (; i < mm; ++i) acc = fmaf(wsh[i], xp[(size_t)i*CD], acc);
    }
    out[(size_t)b * CD + c] = acc;
}

// ---------- launcher ----------
extern "C" void kernel_launch(void* const* d_in, const int* in_sizes, int n_in,
                              void* d_out, int out_size, void* d_ws, size_t ws_size,
                              hipStream_t stream)
{
    const float* x  = (const float*)d_in[0];
    const void*  batch = d_in[1];
    const float* Wt = (const float*)d_in[3];
    const float* bt = (const float*)d_in[4];
    const float* Wg = (const float*)d_in[5];
    const float* bg = (const float*)d_in[6];
    float* out = (float*)d_out;
    const int n = in_sizes[1];            // 400000
    const int nseg = out_size / CD;       // 1024

    char* ws = (char*)d_ws;
    size_t off = 0;
    unsigned short* wtb = (unsigned short*)(ws + off); off += (size_t)HD * CD * 2;
    float* logits = (float*)(ws + off); off += (size_t)n * 4;
    int* batch32  = (int*)(ws + off);   off += (size_t)n * 4;

    hipLaunchKernelGGL(prep_kernel, dim3(576), dim3(256), 0, stream, Wt, wtb, batch, batch32, n);
    hipLaunchKernelGGL(gate_kernel, dim3((n + 127) / 128), dim3(256), 0, stream,
                       x, wtb, bt, Wg, bg, logits, n);
    hipLaunchKernelGGL(segpool_kernel, dim3(nseg), dim3(256), 0, stream,
                       x, logits, batch32, out, n);
}